// Round 2
// baseline (147.288 us; speedup 1.0000x reference)
//
#include <hip/hip_runtime.h>

#define IMG_W 512
#define IMG_H 512
#define BATCH 64
#define SLAB_ROWS 16
#define SLABS (IMG_H / SLAB_ROWS)   // 32 slabs/image
#define NBLOCKS (BATCH * SLABS)     // 2048 blocks x 256 threads
#define NPIX (BATCH * IMG_W * IMG_H)
#define LDS_ROWS 18                 // 16 output rows + 2 halo

typedef float f32x4 __attribute__((ext_vector_type(4)));

__device__ __forceinline__ float fast_sqrtf(float x) {
    return __builtin_amdgcn_sqrtf(x);
}

// R10: LDS-staged restructure. R9's 24 asm-volatile reg-loads plateaued at
// ~44us (VGPR=76 shows the 96-VGPR payload was never simultaneously live as
// intended). Counters: 4.6 TB/s effective delivery (sub-ceiling), VALUBusy
// 25%, occupancy 21.5% -> bursty issue, not a BW wall. Fix: block stages the
// 18 unique rows (36 KB) via global_load_lds w=16 (guide m97 pattern),
// 4 waves share them -> traffic 201->147 MB, tiny VGPR, 4 blocks/CU whose
// staggered stage/compute phases keep both pipes busy (m114 overlap).

typedef const __attribute__((address_space(1))) void gas_void;
typedef __attribute__((address_space(3))) void las_void;

__device__ __forceinline__ void gload_lds16(const float* g, float* l) {
    __builtin_amdgcn_global_load_lds((gas_void*)g, (las_void*)l, 16, 0, 0);
}

// 10-wide window from two f32x4 + shfl halo (image x-edges -> 0).
#define MKWIN(W, A, B)                                                         \
    float W[10];                                                               \
    {                                                                          \
        float l_ = __shfl_up((B)[3], 1, 64);                                   \
        float r_ = __shfl_down((A)[0], 1, 64);                                 \
        W[0] = (lane == 0) ? 0.f : l_;                                         \
        W[1] = (A)[0]; W[2] = (A)[1]; W[3] = (A)[2]; W[4] = (A)[3];            \
        W[5] = (B)[0]; W[6] = (B)[1]; W[7] = (B)[2]; W[8] = (B)[3];            \
        W[9] = (lane == 63) ? 0.f : r_;                                        \
    }

// horizontal 1-2-1 sums of one row (8 wide)
#define MKHS(HS, W)                                                            \
    float HS[8];                                                               \
    _Pragma("unroll")                                                          \
    for (int j = 0; j < 8; ++j)                                                \
        HS[j] = fmaf(2.f, W[j + 1], W[j]) + W[j + 2];

// output row O of image p: store magnitudes
#define DO_OUT_P(O, WA, WB, WC, HSA, HSC)                                      \
    {                                                                          \
        float c_[10];                                                          \
        _Pragma("unroll")                                                      \
        for (int k = 0; k < 10; ++k)                                           \
            c_[k] = fmaf(2.f, WB[k], WA[k]) + WC[k];                           \
        _Pragma("unroll")                                                      \
        for (int j = 0; j < 8; ++j) {                                          \
            float gh = HSC[j] - HSA[j];                                        \
            float gv = c_[j + 2] - c_[j];                                      \
            magp[O][j] = fast_sqrtf(fmaf(gv, gv, fmaf(gh, gh, 1e-18f)));       \
        }                                                                      \
    }

// output row O of image t: fuse |magt - magp| accumulation (no magt array)
#define DO_OUT_T(O, WA, WB, WC, HSA, HSC)                                      \
    {                                                                          \
        float c_[10];                                                          \
        _Pragma("unroll")                                                      \
        for (int k = 0; k < 10; ++k)                                           \
            c_[k] = fmaf(2.f, WB[k], WA[k]) + WC[k];                           \
        _Pragma("unroll")                                                      \
        for (int j = 0; j < 8; ++j) {                                          \
            float gh = HSC[j] - HSA[j];                                        \
            float gv = c_[j + 2] - c_[j];                                      \
            float mt = fast_sqrtf(fmaf(gv, gv, fmaf(gh, gh, 1e-18f)));         \
            lsum += fabsf(mt - magp[O][j]); /* == sqrt(d^2+eps)*(d^2!=0) */    \
        }                                                                      \
    }

#define SOBEL_P(A0, B0, A1, B1, A2, B2, A3, B3, A4, B4, A5, B5)                \
    {                                                                          \
        MKWIN(w0_, A0, B0) MKWIN(w1_, A1, B1) MKWIN(w2_, A2, B2)               \
        MKWIN(w3_, A3, B3) MKWIN(w4_, A4, B4) MKWIN(w5_, A5, B5)               \
        MKHS(h0_, w0_) MKHS(h1_, w1_) MKHS(h2_, w2_)                           \
        MKHS(h3_, w3_) MKHS(h4_, w4_) MKHS(h5_, w5_)                           \
        DO_OUT_P(0, w0_, w1_, w2_, h0_, h2_)                                   \
        DO_OUT_P(1, w1_, w2_, w3_, h1_, h3_)                                   \
        DO_OUT_P(2, w2_, w3_, w4_, h2_, h4_)                                   \
        DO_OUT_P(3, w3_, w4_, w5_, h3_, h5_)                                   \
    }

#define SOBEL_T(A0, B0, A1, B1, A2, B2, A3, B3, A4, B4, A5, B5)                \
    {                                                                          \
        MKWIN(w0_, A0, B0) MKWIN(w1_, A1, B1) MKWIN(w2_, A2, B2)               \
        MKWIN(w3_, A3, B3) MKWIN(w4_, A4, B4) MKWIN(w5_, A5, B5)               \
        MKHS(h0_, w0_) MKHS(h1_, w1_) MKHS(h2_, w2_)                           \
        MKHS(h3_, w3_) MKHS(h4_, w4_) MKHS(h5_, w5_)                           \
        DO_OUT_T(0, w0_, w1_, w2_, h0_, h2_)                                   \
        DO_OUT_T(1, w1_, w2_, w3_, h1_, h3_)                                   \
        DO_OUT_T(2, w2_, w3_, w4_, h2_, h4_)                                   \
        DO_OUT_T(3, w3_, w4_, w5_, h3_, h5_)                                   \
    }

// Stage the 18 (y-clamped) rows of img into smem. 36 chunks of 1 KB; wave w
// issues chunks w*9..w*9+8. LDS dest is linear (global_load_lds constraint:
// uniform base + lane*16), source rows are row-major so layouts match.
#define STAGE_IMG(IMG)                                                         \
    {                                                                          \
        _Pragma("unroll")                                                      \
        for (int k = 0; k < 9; ++k) {                                          \
            const int c = w * 9 + k;            /* chunk 0..35, wave-uniform */\
            int ys = row0 + (c >> 1);                                          \
            ys = ys < 0 ? 0 : (ys > IMG_H - 1 ? IMG_H - 1 : ys);               \
            gload_lds16((IMG) + ((size_t)ys << 9) + ((c & 1) << 8) + (lane << 2), \
                        smem + (c << 8) + (lane << 2));                        \
        }                                                                      \
    }

// Load the wave's 6 rows (block-local rows 4w..4w+5) as A/B f32x4 pairs.
#define LDS_ROWS_TO_REGS()                                                     \
    A0 = s4[rbase + 0 * 128 + cidx]; B0 = s4[rbase + 0 * 128 + cidx + 1];      \
    A1 = s4[rbase + 1 * 128 + cidx]; B1 = s4[rbase + 1 * 128 + cidx + 1];      \
    A2 = s4[rbase + 2 * 128 + cidx]; B2 = s4[rbase + 2 * 128 + cidx + 1];      \
    A3 = s4[rbase + 3 * 128 + cidx]; B3 = s4[rbase + 3 * 128 + cidx + 1];      \
    A4 = s4[rbase + 4 * 128 + cidx]; B4 = s4[rbase + 4 * 128 + cidx + 1];      \
    A5 = s4[rbase + 5 * 128 + cidx]; B5 = s4[rbase + 5 * 128 + cidx + 1];

__global__ __launch_bounds__(256) void sobel_loss_kernel(
    const float* __restrict__ yp, const float* __restrict__ yt,
    float* __restrict__ bsums)
{
    __shared__ float smem[LDS_ROWS * IMG_W];   // 36 KB
    __shared__ float wred[4];

    const int tid  = threadIdx.x;
    const int lane = tid & 63;
    const int w    = tid >> 6;                  // wave id 0..3

    // XCD-contiguous swizzle (bijective: 2048 % 8 == 0): each XCD gets 256
    // consecutive slab-tasks -> adjacent slabs' shared halo rows hit its L2.
    const int bid0 = blockIdx.x;
    const int bid  = (bid0 & 7) * (NBLOCKS / 8) + (bid0 >> 3);

    const int b    = bid >> 5;                  // image (32 slabs/image)
    const int slab = bid & (SLABS - 1);
    const int row0 = slab * SLAB_ROWS - 1;      // top halo source row (may be -1)
    const int ty   = slab * SLAB_ROWS + (w << 2);  // wave's first output row

    const float* imgp = yp + ((size_t)b << 18);
    const float* imgt = yt + ((size_t)b << 18);

    const f32x4* s4 = (const f32x4*)smem;
    const int rbase = (w << 2) * (IMG_W / 4);   // block-local row 4w, in f32x4
    const int cidx  = lane << 1;                // lane*8 floats = lane*2 f32x4

    const f32x4 z4 = {0.f, 0.f, 0.f, 0.f};
    f32x4 A0, B0, A1, B1, A2, B2, A3, B3, A4, B4, A5, B5;

    float magp[4][8];
    float lsum = 0.f;

    // ---- phase P: stage -> barrier -> compute magnitudes ----
    STAGE_IMG(imgp)
    __syncthreads();                            // drains vmcnt(0) + barrier

    LDS_ROWS_TO_REGS()
    if (ty == 0)         { A0 = z4; B0 = z4; }  // 'SAME' zero pad (y)
    if (ty + 4 == IMG_H) { A5 = z4; B5 = z4; }
    SOBEL_P(A0, B0, A1, B1, A2, B2, A3, B3, A4, B4, A5, B5)

    __syncthreads();                            // all waves done reading p

    // ---- phase T: stage into same buffer -> barrier -> fused diff ----
    STAGE_IMG(imgt)
    __syncthreads();

    LDS_ROWS_TO_REGS()
    if (ty == 0)         { A0 = z4; B0 = z4; }
    if (ty + 4 == IMG_H) { A5 = z4; B5 = z4; }
    SOBEL_T(A0, B0, A1, B1, A2, B2, A3, B3, A4, B4, A5, B5)

    // ---- Block reduction ----
#pragma unroll
    for (int off = 32; off > 0; off >>= 1)
        lsum += __shfl_down(lsum, off, 64);
    if (lane == 0) wred[w] = lsum;
    __syncthreads();
    if (tid == 0)
        bsums[blockIdx.x] = wred[0] + wred[1] + wred[2] + wred[3];
}

__global__ __launch_bounds__(256) void reduce_final(
    const float* __restrict__ bsums, float* __restrict__ out)
{
    __shared__ float wred[4];
    const int tid = threadIdx.x;
    float s = 0.f;
    for (int i = tid; i < NBLOCKS; i += 256) s += bsums[i];
#pragma unroll
    for (int off = 32; off > 0; off >>= 1)
        s += __shfl_down(s, off, 64);
    if ((tid & 63) == 0) wred[tid >> 6] = s;
    __syncthreads();
    if (tid == 0)
        out[0] = (wred[0] + wred[1] + wred[2] + wred[3]) * (1.0f / (float)NPIX);
}

extern "C" void kernel_launch(void* const* d_in, const int* in_sizes, int n_in,
                              void* d_out, int out_size, void* d_ws, size_t ws_size,
                              hipStream_t stream) {
    const float* yp = (const float*)d_in[0];
    const float* yt = (const float*)d_in[1];
    float* out = (float*)d_out;

    float* bsums = (float*)d_ws;   // 8 KB of workspace
    sobel_loss_kernel<<<NBLOCKS, 256, 0, stream>>>(yp, yt, bsums);
    reduce_final<<<1, 256, 0, stream>>>(bsums, out);
}